// Round 9
// baseline (447.127 us; speedup 1.0000x reference)
//
#include <hip/hip_runtime.h>

#define HW    36864
#define NB    4
#define NCH   256
#define CIN   64
#define CB    16
#define NPIX  (NB*HW)          // 147456
#define DELTA 1e-4f

typedef short bf16x8 __attribute__((ext_vector_type(8)));
typedef float f32x4  __attribute__((ext_vector_type(4)));

struct FlagEntry {
  unsigned pix;
  unsigned char cnt, need, r0, r1;   // r0 = full-f64-redo flag
  unsigned char ks[8];
};                              // 16 B

// ---------------- bf16 split helpers (RNE) -----------------------------------

__device__ __forceinline__ unsigned short bf16_rne(float x) {
  unsigned u = __float_as_uint(x);
  unsigned r = u + 0x7fffu + ((u >> 16) & 1u);
  return (unsigned short)(r >> 16);
}
__device__ __forceinline__ float bf16_tof(unsigned short h) {
  return __uint_as_float(((unsigned)h) << 16);
}

// ---------------- sorting networks (values only, fully unrolled) -------------

template<bool ASC>
__device__ __forceinline__ void bitonic16(float* v) {
  #pragma unroll
  for (int K = 2; K <= 16; K <<= 1) {
    #pragma unroll
    for (int J = K >> 1; J > 0; J >>= 1) {
      #pragma unroll
      for (int i = 0; i < 16; ++i) {
        int l = i ^ J;
        if (l > i) {
          bool up = (((i & K) == 0) == ASC);
          float a = v[i], b = v[l];
          float lo = fminf(a, b), hi = fmaxf(a, b);
          v[i] = up ? lo : hi;
          v[l] = up ? hi : lo;
        }
      }
    }
  }
}

__device__ __forceinline__ void bmerge16_desc(float* v) {
  #pragma unroll
  for (int J = 8; J > 0; J >>= 1) {
    #pragma unroll
    for (int i = 0; i < 16; ++i) {
      int l = i ^ J;
      if (l > i) {
        float a = v[i], b = v[l];
        float lo = fminf(a, b), hi = fmaxf(a, b);
        v[i] = hi; v[l] = lo;
      }
    }
  }
}

// ---------------- K0: zero flag counter --------------------------------------

__global__ void k0_zero(unsigned* flagcnt) { *flagcnt = 0u; }

// ---------------- K1: 1x1 conv (64->16) + f64 stats partials -----------------

__global__ __launch_bounds__(256) void k1_conv(
    const float* __restrict__ bfeat, const float* __restrict__ wb,
    const float* __restrict__ bb, float* __restrict__ xout,
    double* __restrict__ part)
{
  __shared__ float wbT[CIN][CB];          // 4 KB
  __shared__ double redS[4][CB];
  __shared__ double redQ[4][CB];
  const int t = threadIdx.x;
  for (int i = t; i < CIN*CB; i += 256) {
    int o = i >> 6, c = i & 63;
    wbT[c][o] = wb[i];
  }
  __syncthreads();

  const int blk = blockIdx.x;             // 576
  const int b = blk / 144, seg = blk % 144;
  const int p = seg * 256 + t;
  const float* bfb = bfeat + (size_t)b * CIN * HW;

  float acc[CB];
  #pragma unroll
  for (int o = 0; o < CB; ++o) acc[o] = bb[o];

  for (int c = 0; c < CIN; ++c) {
    float v = bfb[(size_t)c*HW + p];
    #pragma unroll
    for (int o4 = 0; o4 < 4; ++o4) {
      float4 w4 = *(const float4*)&wbT[c][o4*4];
      acc[o4*4+0] = fmaf(v, w4.x, acc[o4*4+0]);
      acc[o4*4+1] = fmaf(v, w4.y, acc[o4*4+1]);
      acc[o4*4+2] = fmaf(v, w4.z, acc[o4*4+2]);
      acc[o4*4+3] = fmaf(v, w4.w, acc[o4*4+3]);
    }
  }

  float* xb = xout + (size_t)b * CB * HW;
  #pragma unroll
  for (int o = 0; o < CB; ++o) xb[(size_t)o*HW + p] = acc[o];

  const int wv = t >> 6, lane = t & 63;
  #pragma unroll
  for (int o = 0; o < CB; ++o) {
    double a = (double)acc[o], q = a*a;
    for (int off = 32; off; off >>= 1) { a += __shfl_xor(a, off); q += __shfl_xor(q, off); }
    if (lane == 0) { redS[wv][o] = a; redQ[wv][o] = q; }
  }
  __syncthreads();
  if (t < CB) {
    double a = redS[0][t] + redS[1][t] + redS[2][t] + redS[3][t];
    part[(size_t)blk*32 + t] = a;
  } else if (t < 32) {
    int o = t - CB;
    double q = redQ[0][o] + redQ[1][o] + redQ[2][o] + redQ[3][o];
    part[(size_t)blk*32 + t] = q;
  }
}

// ---------------- K1b: finalize BN stats -------------------------------------

__global__ __launch_bounds__(64) void k1b_stats(
    const double* __restrict__ part, const float* __restrict__ gam,
    const float* __restrict__ bet, double* __restrict__ st64, float* __restrict__ st32)
{
  __shared__ double sh[32];
  const int t = threadIdx.x;
  if (t < 32) {
    double a = 0.0;
    #pragma unroll 8
    for (int i = 0; i < 576; ++i) a += part[(size_t)i*32 + t];
    sh[t] = a;
  }
  __syncthreads();
  if (t < CB) {
    const double N = (double)NPIX;
    double mean = sh[t] / N;
    double var  = sh[16+t] / N - mean*mean;
    double rstd = 1.0 / sqrt(var + 1e-5);
    double scl = (double)gam[t] * rstd;
    double sft = (double)bet[t] - mean*scl;
    st64[t] = scl; st64[CB+t] = sft;
    st32[t] = (float)scl; st32[CB+t] = (float)sft;
  }
}

// ---------------- K1c: build split-bf16 B fragments for MFMA -----------------

__global__ __launch_bounds__(256) void k1c_bfrag(
    const float* __restrict__ wm, short* __restrict__ bfrag)
{
  const int t = threadIdx.x;
  for (int e = t; e < 2048; e += 256) {       // (v, ct, lane)
    const int v = e >> 10, ct = (e >> 6) & 15, l = e & 63;
    const int n = l & 15, g = l >> 4;
    const int col = ct*16 + n;
    short out[8];
    #pragma unroll
    for (int j = 0; j < 8; ++j) {
      const int k = g*8 + j;
      const int kk = k & 15;
      const bool hi_half = (k < 16);
      float w = wm[col*CB + kk];
      unsigned short hb = bf16_rne(w);
      float res = w - bf16_tof(hb);
      unsigned short lb = bf16_rne(res);
      bool use_hi = ((v == 0) == hi_half);
      out[j] = (short)(use_hi ? hb : lb);
    }
    bf16x8 pk;
    #pragma unroll
    for (int j = 0; j < 8; ++j) pk[j] = out[j];
    *(bf16x8*)&bfrag[(size_t)e * 8] = pk;
  }
}

// ---------------- K2: fused MFMA + selection ---------------------------------
// 3072 blocks x 256 threads; 48 pixels/block; 54144 B dynamic LDS (3 blk/CU).

__device__ __forceinline__ void k2_epilogue(int b, int p, int pxl,
    int selN, int nearN, int nselN,
    float* lcw, unsigned char* lidx, unsigned char* lnear,
    unsigned* cidx, float* cw, unsigned* flagcnt, FlagEntry* entries)
{
  int start = selN < 16 ? selN : 16;
  for (int j = start; j < 16; ++j) { lcw[pxl*16 + j] = 0.f; lidx[pxl*16 + j] = 0; }
  unsigned g = (unsigned)(b*HW + p);
  uint4 iv = *(uint4*)&lidx[pxl*16];
  ((uint4*)cidx)[g] = iv;
  float4* cwq = (float4*)cw;
  #pragma unroll
  for (int q = 0; q < 4; ++q) cwq[(size_t)g*4 + q] = *(float4*)&lcw[pxl*16 + q*4];
  bool flag = (nearN > 1) || (selN != 16);
  if (flag) {
    unsigned slot = atomicAdd(flagcnt, 1u);
    FlagEntry e;
    e.pix = g;
    int cnt = nearN < 8 ? nearN : 8;
    e.cnt = (unsigned char)cnt;
    int nsure = selN - nselN;
    int need = 16 - nsure;
    if (need < 0) need = 0;
    if (need > cnt) need = cnt;
    e.need = (unsigned char)need;
    e.r0 = (nearN > 8 || selN != 16) ? 1 : 0;
    e.r1 = 0;
    #pragma unroll
    for (int j = 0; j < 8; ++j) e.ks[j] = (j < cnt) ? lnear[pxl*8 + j] : 0;
    entries[slot] = e;
  }
}

#define MSTRIDE 260
#define PXB 48

__global__ __launch_bounds__(256, 3) void k2_main(
    const float* __restrict__ x, const short* __restrict__ bfrag,
    const float* __restrict__ st32, float* __restrict__ msp,
    unsigned* __restrict__ cidx, float* __restrict__ cw,
    unsigned* __restrict__ flagcnt, FlagEntry* __restrict__ entries)
{
  extern __shared__ char smem[];
  float* m_lds = (float*)smem;                          // [48][260] = 49920 B
  char* uni = smem + PXB*MSTRIDE*4;                     // 4224 B union
  float* lcw = (float*)uni;                             // [48][16] = 3072
  unsigned char* lidx  = (unsigned char*)(uni + 3072);  // [48][16] = 768
  unsigned char* lnear = (unsigned char*)(uni + 3840);  // [48][8]  = 384
  short* A_st = (short*)uni;                            // [48][40] = 3840 (phases 0-1)

  const int t = threadIdx.x;
  const int blk = blockIdx.x;                           // 3072
  const int b = blk / 768;
  const int p0 = (blk % 768) * PXB;
  const float* xb = x + (size_t)b*CB*HW + p0;

  // ---- phase 0: load x rows, BN+ReLU, split to bf16 hi/lo, stage A ----
  for (int idx = t; idx < PXB*CB; idx += 256) {
    int o = idx / PXB, pl = idx % PXB;
    float vx = xb[(size_t)o*HW + pl];
    float f = fmaxf(0.f, fmaf(vx, st32[o], st32[CB+o]));
    unsigned short hb = bf16_rne(f);
    float res = f - bf16_tof(hb);
    unsigned short lb = bf16_rne(res);
    A_st[pl*40 + o]      = (short)hb;
    A_st[pl*40 + 16 + o] = (short)lb;
  }
  __syncthreads();

  const int w = t >> 6, l = t & 63;

  // ---- phase 1: MFMA; 48 tile-units (3 row-tiles x 16 ct), 12 per wave ----
  {
    const int coln = l & 15;
    const int k0 = (l >> 4) * 8;
    #pragma unroll
    for (int uu = 0; uu < 12; ++uu) {
      const int u = w*12 + uu;
      const int rt = u >> 4, ct = u & 15;
      const int prow = rt*16 + coln;
      bf16x8 a = *(const bf16x8*)&A_st[prow*40 + k0];
      bf16x8 b1 = *(const bf16x8*)&bfrag[(size_t)(ct*64 + l)*8];
      bf16x8 b2 = *(const bf16x8*)&bfrag[(size_t)((16 + ct)*64 + l)*8];
      f32x4 acc = {0.f, 0.f, 0.f, 0.f};
      acc = __builtin_amdgcn_mfma_f32_16x16x32_bf16(a, b1, acc, 0, 0, 0);
      acc = __builtin_amdgcn_mfma_f32_16x16x32_bf16(a, b2, acc, 0, 0, 0);
      const int rowo = rt*16 + (l >> 4)*4;
      #pragma unroll
      for (int i = 0; i < 4; ++i)
        m_lds[(rowo + i)*MSTRIDE + ct*16 + coln] = acc[i];
    }
  }
  __syncthreads();   // also protects uni reuse (A_st -> lcw/lidx/lnear)

  // ---- phases 2-3: selection; 4 lanes per pixel, 64 colors each ----
  const int p = t >> 2, q = t & 3;
  if (p < PXB) {
    float mv[64];
    #pragma unroll
    for (int r = 0; r < 16; ++r) {
      const int c = (r + q*4) & 15;              // rotated chunk order
      f32x4 v4 = *(const f32x4*)&m_lds[p*MSTRIDE + q*64 + c*4];
      mv[c*4+0] = v4[0]; mv[c*4+1] = v4[1]; mv[c*4+2] = v4[2]; mv[c*4+3] = v4[3];
    }

    float T[16], tmp[16];
    #pragma unroll
    for (int i = 0; i < 16; ++i) tmp[i] = mv[i];
    bitonic16<false>(tmp);
    #pragma unroll
    for (int i = 0; i < 16; ++i) T[i] = tmp[i];
    #pragma unroll
    for (int c = 1; c < 4; ++c) {
      #pragma unroll
      for (int i = 0; i < 16; ++i) tmp[i] = mv[c*16 + i];
      bitonic16<true>(tmp);
      #pragma unroll
      for (int i = 0; i < 16; ++i) T[i] = fmaxf(T[i], tmp[i]);
      bmerge16_desc(T);
    }
    // cross-lane merges among the 4 lanes of this pixel
    {
      float R[16];
      #pragma unroll
      for (int i = 0; i < 16; ++i) R[i] = fmaxf(T[i], __shfl_xor(T[15-i], 1));
      bmerge16_desc(R);
      #pragma unroll
      for (int i = 0; i < 16; ++i) T[i] = R[i];
      #pragma unroll
      for (int i = 0; i < 16; ++i) R[i] = fmaxf(T[i], __shfl_xor(T[15-i], 2));
      bmerge16_desc(R);
      #pragma unroll
      for (int i = 0; i < 16; ++i) T[i] = R[i];
    }
    const float tau = T[15], top = T[0];
    float Z = 0.f;
    #pragma unroll
    for (int i = 0; i < 16; ++i) Z += __expf(T[i] - top);
    const float iZ = 1.f / Z;

    // ---- phase 3a: per-lane counts + 4-lane prefix ----
    int cs = 0, cn = 0, cns = 0;
    #pragma unroll
    for (int j = 0; j < 64; ++j) {
      float v = mv[j];
      bool s = (v >= tau);
      bool nr = (fabsf(v - tau) <= DELTA);
      cs += s ? 1 : 0; cn += nr ? 1 : 0; cns += (s && nr) ? 1 : 0;
    }
    const int lb_ = l & ~3;
    int c0 = __shfl(cs, lb_), c1 = __shfl(cs, lb_+1), c2 = __shfl(cs, lb_+2), c3 = __shfl(cs, lb_+3);
    int n0 = __shfl(cn, lb_), n1 = __shfl(cn, lb_+1), n2 = __shfl(cn, lb_+2), n3 = __shfl(cn, lb_+3);
    int s0 = __shfl(cns, lb_), s1 = __shfl(cns, lb_+1), s2 = __shfl(cns, lb_+2), s3 = __shfl(cns, lb_+3);
    int offs = (q > 0 ? c0 : 0) + (q > 1 ? c1 : 0) + (q > 2 ? c2 : 0);
    int offn = (q > 0 ? n0 : 0) + (q > 1 ? n1 : 0) + (q > 2 ? n2 : 0);
    const int selN = c0 + c1 + c2 + c3;
    const int nearN = n0 + n1 + n2 + n3;
    const int nselN = s0 + s1 + s2 + s3;

    // ---- phase 3b: dense write + compact/near lists ----
    float* mspb = msp + (size_t)b*NCH*HW + p0;
    int isel = 0, inear = 0;
    #pragma unroll
    for (int j = 0; j < 64; ++j) {
      const int k = q*64 + j;
      float v = mv[j];
      bool s = (v >= tau);
      bool nr = (fabsf(v - tau) <= DELTA);
      float wv = s ? __expf(v - top) * iZ : 0.f;
      mspb[(size_t)k*HW + p] = wv;
      if (s) {
        int slot = offs + isel;
        if (slot < 16) { lcw[p*16 + slot] = wv; lidx[p*16 + slot] = (unsigned char)k; }
        ++isel;
      }
      if (nr) {
        int gs = offn + inear;
        if (gs < 8) lnear[p*8 + gs] = (unsigned char)k;
        ++inear;
      }
    }

    // ---- phase 3c: epilogue (one lane per pixel) ----
    if (q == 0)
      k2_epilogue(b, p0 + p, p, selN, nearN, nselN, lcw, lidx, lnear,
                  cidx, cw, flagcnt, entries);
  }
}

// ---------------- K2b: wave-cooperative fixup for near-boundary pixels -------

__global__ __launch_bounds__(64) void k2b_fix(
    const float* __restrict__ bfeat, const float* __restrict__ wb,
    const float* __restrict__ bb, const float* __restrict__ wmg,
    const double* __restrict__ st64,
    const unsigned* __restrict__ flagcnt, const FlagEntry* __restrict__ entries,
    float* __restrict__ msp, unsigned* __restrict__ cidx, float* __restrict__ cw)
{
  __shared__ float wbT[CB][CIN];     // 4 KB: wbT[o][c] = wb[o*CIN+c]
  __shared__ float  wOrigL[16];
  __shared__ int    kOrigL[16];
  __shared__ float  wnL[8];
  __shared__ int    kL[8];
  __shared__ double tvL[16];
  __shared__ int    tiL[16];
  __shared__ float  wvL[16];

  const int lane = threadIdx.x;
  for (int i = lane; i < CB*CIN; i += 64) wbT[i >> 6][i & 63] = wb[i];
  __syncthreads();

  const unsigned n = *flagcnt;
  for (unsigned idx = blockIdx.x; idx < n; idx += gridDim.x) {
    FlagEntry e = entries[idx];
    const int b = (int)(e.pix / HW), p = (int)(e.pix % HW);

    // ---- f64 conv (wave-parallel over channels) + BN + ReLU ----
    const double v = (double)bfeat[(size_t)b*CIN*HW + (size_t)lane*HW + p];
    double ft[CB];
    #pragma unroll
    for (int o = 0; o < CB; ++o) {
      double s = v * (double)wbT[o][lane];
      #pragma unroll
      for (int off = 32; off; off >>= 1) s += __shfl_xor(s, off);
      s += (double)bb[o];                       // all lanes hold same value
      ft[o] = fmax(0.0, s*st64[o] + st64[CB+o]);
    }

    float* mb = msp + (size_t)b*NCH*HW;
    unsigned char* cb_ = (unsigned char*)cidx + (size_t)e.pix*16;
    float* cwp = cw + (size_t)e.pix*16;

    if (e.r0) {
      // ---- full f64 redo: wave-parallel top-16, (value desc, index asc) ----
      double mm[4]; int kk4[4];
      #pragma unroll
      for (int u = 0; u < 4; ++u) {
        const int k = lane + 64*u; kk4[u] = k;
        const float* wr = wmg + k*CB;
        double a = 0.0;
        #pragma unroll
        for (int c = 0; c < CB; ++c) a = fma(ft[c], (double)wr[c], a);
        mm[u] = a;
      }
      for (int j = 0; j < 16; ++j) {
        double bm = mm[0]; int bk = kk4[0];
        #pragma unroll
        for (int u = 1; u < 4; ++u) {
          bool gt = (mm[u] > bm) || (mm[u] == bm && kk4[u] < bk);
          if (gt) { bm = mm[u]; bk = kk4[u]; }
        }
        #pragma unroll
        for (int off = 32; off; off >>= 1) {
          double om = __shfl_xor(bm, off);
          int ok = __shfl_xor(bk, off);
          bool gt = (om > bm) || (om == bm && ok < bk);
          if (gt) { bm = om; bk = ok; }
        }
        if (lane == 0) { tvL[j] = bm; tiL[j] = bk; }
        #pragma unroll
        for (int u = 0; u < 4; ++u) if (kk4[u] == bk) mm[u] = -1.0e300;
      }
      __syncthreads();
      const double top = tvL[0];
      double ej = (lane < 16) ? exp(tvL[lane] - top) : 0.0;
      double Z = ej;
      #pragma unroll
      for (int off = 32; off; off >>= 1) Z += __shfl_xor(Z, off);
      if (lane < 16) wvL[lane] = (float)(ej / Z);
      __syncthreads();
      int tiR[16]; float wvR[16];
      #pragma unroll
      for (int j = 0; j < 16; ++j) { tiR[j] = tiL[j]; wvR[j] = wvL[j]; }
      // dense write: 4 colors per lane
      #pragma unroll
      for (int u = 0; u < 4; ++u) {
        const int k = lane + 64*u;
        float wv = 0.f;
        #pragma unroll
        for (int j = 0; j < 16; ++j) if (tiR[j] == k) wv = wvR[j];
        mb[(size_t)k*HW + p] = wv;
      }
      // compact rebuild (ascending k, skip zero weights)
      if (lane == 0) {
        unsigned used = 0; int on = 0;
        for (int it = 0; it < 16; ++it) {
          int bk = 1 << 20;
          #pragma unroll
          for (int j = 0; j < 16; ++j)
            if (!((used >> j) & 1u) && tiR[j] < bk) bk = tiR[j];
          if (bk >= (1 << 20)) break;
          float bw = 0.f;
          #pragma unroll
          for (int j = 0; j < 16; ++j)
            if (tiR[j] == bk) { bw = wvR[j]; used |= (1u << j); }
          if (bw != 0.f && on < 16) { cb_[on] = (unsigned char)bk; cwp[on] = bw; ++on; }
        }
        for (int j = on; j < 16; ++j) { cb_[j] = 0; cwp[j] = 0.f; }
      }
      __syncthreads();
      continue;
    }

    // ---- light path (selN==16 guaranteed; lane-parallel over near colors) ----
    const int cnt = (e.cnt > 8) ? 8 : (int)e.cnt;
    int need = (int)e.need; if (need > cnt) need = cnt;

    if (lane < 16) { wOrigL[lane] = cwp[lane]; kOrigL[lane] = (int)cb_[lane]; }
    __syncthreads();

    const int myk = (lane < cnt) ? (int)e.ks[lane] : 0x7fffffff;
    double mj = 0.0;
    if (lane < cnt) {
      const float* wr = wmg + myk*CB;
      #pragma unroll
      for (int c = 0; c < CB; ++c) mj = fma(ft[c], (double)wr[c], mj);
    }
    float woldj = 0.f;
    if (lane < cnt) {
      #pragma unroll
      for (int q = 0; q < 16; ++q) {
        if (kOrigL[q] == myk && wOrigL[q] > 0.f) woldj = wOrigL[q];
      }
    }
    // rank among the cnt near colors: (m desc, k asc)
    int rankj = 0;
    #pragma unroll
    for (int j2 = 0; j2 < 8; ++j2) {
      double m2 = __shfl(mj, j2);
      int k2v = __shfl(myk, j2);
      if (lane < cnt && j2 < cnt && j2 != lane) {
        bool gt = (m2 > mj) || (m2 == mj && k2v < myk);
        rankj += gt ? 1 : 0;
      }
    }
    // gather all wold; count positives
    float w2[8];
    #pragma unroll
    for (int j2 = 0; j2 < 8; ++j2) w2[j2] = __shfl(woldj, j2);
    int nw = 0;
    #pragma unroll
    for (int j2 = 0; j2 < 8; ++j2) if (j2 < cnt && w2[j2] > 0.f) ++nw;
    // rank-th largest positive wold (equal values interchangeable)
    float wnj = 0.f;
    if (lane < cnt && rankj < need && rankj < nw) {
      #pragma unroll
      for (int cand = 0; cand < 8; ++cand) {
        if (cand < cnt && w2[cand] > 0.f) {
          float xv = w2[cand];
          int cgt = 0, cge = 0;
          #pragma unroll
          for (int j2 = 0; j2 < 8; ++j2)
            if (j2 < cnt && w2[j2] > 0.f) { cgt += (w2[j2] > xv); cge += (w2[j2] >= xv); }
          if (cgt <= rankj && rankj < cge) wnj = xv;
        }
      }
    }
    if (lane < cnt) mb[(size_t)myk*HW + p] = wnj;   // dense updates
    if (lane < 8)  { wnL[lane] = wnj; kL[lane] = myk; }
    __syncthreads();

    if (lane == 0) {
      // merge original compact (asc k) with near-color updates
      int on = 0, ii = 0, jj = 0;
      while (ii < 16 || jj < cnt) {
        if (ii < 16 && wOrigL[ii] <= 0.f) { ++ii; continue; }
        int ko = (ii < 16) ? kOrigL[ii] : (1 << 20);
        int kj = (jj < cnt) ? kL[jj] : (1 << 20);
        if (ko >= (1 << 20) && kj >= (1 << 20)) break;
        if (ko < kj) {
          if (on < 16) { cb_[on] = (unsigned char)ko; cwp[on] = wOrigL[ii]; ++on; }
          ++ii;
        } else if (kj < ko) {
          if (wnL[jj] > 0.f && on < 16) { cb_[on] = (unsigned char)kj; cwp[on] = wnL[jj]; ++on; }
          ++jj;
        } else {
          if (wnL[jj] > 0.f && on < 16) { cb_[on] = (unsigned char)kj; cwp[on] = wnL[jj]; ++on; }
          ++ii; ++jj;
        }
      }
      for (int j = on; j < 16; ++j) { cb_[j] = 0; cwp[j] = 0.f; }
    }
    __syncthreads();
  }
}

// ---------------- K3: num/den accumulation -----------------------------------

__global__ __launch_bounds__(256) void k3_accum(
    const uint4* __restrict__ cidx, const float4* __restrict__ cw4,
    const float* __restrict__ img, float* __restrict__ part)
{
  __shared__ float acc[1024];
  const int t = threadIdx.x, blk = blockIdx.x;
  for (int i = t; i < 1024; i += 256) acc[i] = 0.f;
  __syncthreads();
  const int b = blk / 144;
  const int p = (blk % 144) * 256 + t;
  const float* imb = img + (size_t)b*3*HW;
  const int g = b*HW + p;
  uint4 iv = cidx[g];
  unsigned ivq[4] = {iv.x, iv.y, iv.z, iv.w};
  float r = imb[p], g_ = imb[HW + p], bl = imb[2*HW + p];
  #pragma unroll
  for (int q = 0; q < 4; ++q) {
    float4 wv = cw4[(size_t)g*4 + q];
    float wvv[4] = {wv.x, wv.y, wv.z, wv.w};
    #pragma unroll
    for (int u = 0; u < 4; ++u) {
      int k = (int)((ivq[q] >> (8*u)) & 255u);
      float wgt = wvv[u];
      atomicAdd(&acc[k],       wgt * r);
      atomicAdd(&acc[256 + k], wgt * g_);
      atomicAdd(&acc[512 + k], wgt * bl);
      atomicAdd(&acc[768 + k], wgt);
    }
  }
  __syncthreads();
  for (int i = t; i < 1024; i += 256) part[(size_t)blk*1024 + i] = acc[i];
}

// ---------------- K4: palette ------------------------------------------------

__global__ __launch_bounds__(256) void k4_pal(
    const float* __restrict__ part, float* __restrict__ out_pal)
{
  __shared__ float acc[1024];
  const int b = blockIdx.x, t = threadIdx.x;
  for (int s = t; s < 1024; s += 256) {
    float a = 0.f;
    for (int i = 0; i < 144; ++i) a += part[(size_t)(b*144 + i)*1024 + s];
    acc[s] = a;
  }
  __syncthreads();
  for (int s = t; s < 768; s += 256) {
    int k = s & 255;
    float den = acc[768 + k] + 1e-8f;
    out_pal[(size_t)b*768 + s] = acc[s] / den;
  }
}

// ---------------- K5: recolored image ----------------------------------------

__global__ __launch_bounds__(256) void k5_img(
    const uint4* __restrict__ cidx, const float4* __restrict__ cw4,
    const float* __restrict__ pal, float* __restrict__ outimg)
{
  __shared__ float lp[768];
  const int t = threadIdx.x, blk = blockIdx.x;
  const int b = blk / 144;
  for (int i = t; i < 768; i += 256) lp[i] = pal[(size_t)b*768 + i];
  __syncthreads();
  const int p = (blk % 144) * 256 + t;
  const int g = b*HW + p;
  uint4 iv = cidx[g];
  unsigned ivq[4] = {iv.x, iv.y, iv.z, iv.w};
  float r = 0.f, g_ = 0.f, bl = 0.f;
  #pragma unroll
  for (int q = 0; q < 4; ++q) {
    float4 wv = cw4[(size_t)g*4 + q];
    float wvv[4] = {wv.x, wv.y, wv.z, wv.w};
    #pragma unroll
    for (int u = 0; u < 4; ++u) {
      int k = (int)((ivq[q] >> (8*u)) & 255u);
      float wgt = wvv[u];
      r  = fmaf(wgt, lp[k],       r);
      g_ = fmaf(wgt, lp[256 + k], g_);
      bl = fmaf(wgt, lp[512 + k], bl);
    }
  }
  float* ob = outimg + (size_t)b*3*HW;
  ob[p] = r; ob[HW + p] = g_; ob[2*HW + p] = bl;
}

// ---------------- launcher ---------------------------------------------------

extern "C" void kernel_launch(void* const* d_in, const int* in_sizes, int n_in,
                              void* d_out, int out_size, void* d_ws, size_t ws_size,
                              hipStream_t stream)
{
  const float* img   = (const float*)d_in[0];
  const float* bfeat = (const float*)d_in[1];
  const float* wb    = (const float*)d_in[2];
  const float* bb    = (const float*)d_in[3];
  const float* gam   = (const float*)d_in[4];
  const float* bet   = (const float*)d_in[5];
  const float* wm    = (const float*)d_in[6];

  float* out_img = (float*)d_out;                 // [4,3,192,192]
  float* out_msp = (float*)d_out + 442368;        // [4,256,192,192]
  float* out_pal = (float*)d_out + 38191104;      // [4,3,256,1,1]

  char* w = (char*)d_ws;
  float*     ws_x       = (float*)(w);                     // 9,437,184 B (dead after k2 -> reused for k3 partials)
  double*    ws_part    = (double*)(w + 9437184);          //   147,456 B
  double*    ws_st64    = (double*)(w + 9584640);          //       256 B
  float*     ws_st32    = (float*)(w + 9584896);           //       128 B
  unsigned*  ws_flagcnt = (unsigned*)(w + 9585152);        //       256 B pad
  FlagEntry* ws_entries = (FlagEntry*)(w + 9585408);       // 2,359,296 B
  unsigned*  ws_cidx    = (unsigned*)(w + 11944704);       // 2,359,296 B
  float*     ws_cw      = (float*)(w + 14304000);          // 9,437,184 B
  float*     ws_nd      = ws_x;                            // aliases ws_x (x dead after k2)
  short*     ws_bfrag   = (short*)(w + 23741184);          //    32,768 B

  k0_zero<<<dim3(1), dim3(1), 0, stream>>>(ws_flagcnt);
  k1_conv<<<dim3(576), dim3(256), 0, stream>>>(bfeat, wb, bb, ws_x, ws_part);
  k1b_stats<<<dim3(1), dim3(64), 0, stream>>>(ws_part, gam, bet, ws_st64, ws_st32);
  k1c_bfrag<<<dim3(1), dim3(256), 0, stream>>>(wm, ws_bfrag);
  k2_main<<<dim3(3072), dim3(256), 54144, stream>>>(ws_x, ws_bfrag, ws_st32, out_msp,
                                                    ws_cidx, ws_cw, ws_flagcnt, ws_entries);
  k2b_fix<<<dim3(4096), dim3(64), 0, stream>>>(bfeat, wb, bb, wm, ws_st64,
                                               ws_flagcnt, ws_entries, out_msp, ws_cidx, ws_cw);
  k3_accum<<<dim3(576), dim3(256), 0, stream>>>((const uint4*)ws_cidx, (const float4*)ws_cw,
                                                img, ws_nd);
  k4_pal<<<dim3(4), dim3(256), 0, stream>>>(ws_nd, out_pal);
  k5_img<<<dim3(576), dim3(256), 0, stream>>>((const uint4*)ws_cidx, (const float4*)ws_cw,
                                              out_pal, out_img);
}

// Round 10
// 297.465 us; speedup vs baseline: 1.5031x; 1.5031x over previous
//
#include <hip/hip_runtime.h>

#define HW    36864
#define NB    4
#define NCH   256
#define CIN   64
#define CB    16
#define NPIX  (NB*HW)          // 147456
#define DELTA 1e-4f

typedef short bf16x8 __attribute__((ext_vector_type(8)));
typedef float f32x4  __attribute__((ext_vector_type(4)));

struct FlagEntry {
  unsigned pix;
  unsigned char cnt, need, r0, r1;   // r0 = full-f64-redo flag
  unsigned char ks[8];
};                              // 16 B

// ---------------- bf16 split helpers (RNE) -----------------------------------

__device__ __forceinline__ unsigned short bf16_rne(float x) {
  unsigned u = __float_as_uint(x);
  unsigned r = u + 0x7fffu + ((u >> 16) & 1u);
  return (unsigned short)(r >> 16);
}
__device__ __forceinline__ float bf16_tof(unsigned short h) {
  return __uint_as_float(((unsigned)h) << 16);
}

// ---------------- sorting networks (values only, fully unrolled) -------------

template<bool ASC>
__device__ __forceinline__ void bitonic16(float* v) {
  #pragma unroll
  for (int K = 2; K <= 16; K <<= 1) {
    #pragma unroll
    for (int J = K >> 1; J > 0; J >>= 1) {
      #pragma unroll
      for (int i = 0; i < 16; ++i) {
        int l = i ^ J;
        if (l > i) {
          bool up = (((i & K) == 0) == ASC);
          float a = v[i], b = v[l];
          float lo = fminf(a, b), hi = fmaxf(a, b);
          v[i] = up ? lo : hi;
          v[l] = up ? hi : lo;
        }
      }
    }
  }
}

__device__ __forceinline__ void bmerge16_desc(float* v) {
  #pragma unroll
  for (int J = 8; J > 0; J >>= 1) {
    #pragma unroll
    for (int i = 0; i < 16; ++i) {
      int l = i ^ J;
      if (l > i) {
        float a = v[i], b = v[l];
        float lo = fminf(a, b), hi = fmaxf(a, b);
        v[i] = hi; v[l] = lo;
      }
    }
  }
}

// ---------------- K0: zero flag counter --------------------------------------

__global__ void k0_zero(unsigned* flagcnt) { *flagcnt = 0u; }

// ---------------- K1: 1x1 conv (64->16) + f64 stats partials -----------------

__global__ __launch_bounds__(256) void k1_conv(
    const float* __restrict__ bfeat, const float* __restrict__ wb,
    const float* __restrict__ bb, float* __restrict__ xout,
    double* __restrict__ part)
{
  __shared__ float wbT[CIN][CB];          // 4 KB
  __shared__ double redS[4][CB];
  __shared__ double redQ[4][CB];
  const int t = threadIdx.x;
  for (int i = t; i < CIN*CB; i += 256) {
    int o = i >> 6, c = i & 63;
    wbT[c][o] = wb[i];
  }
  __syncthreads();

  const int blk = blockIdx.x;             // 576
  const int b = blk / 144, seg = blk % 144;
  const int p = seg * 256 + t;
  const float* bfb = bfeat + (size_t)b * CIN * HW;

  float acc[CB];
  #pragma unroll
  for (int o = 0; o < CB; ++o) acc[o] = bb[o];

  for (int c = 0; c < CIN; ++c) {
    float v = bfb[(size_t)c*HW + p];
    #pragma unroll
    for (int o4 = 0; o4 < 4; ++o4) {
      float4 w4 = *(const float4*)&wbT[c][o4*4];
      acc[o4*4+0] = fmaf(v, w4.x, acc[o4*4+0]);
      acc[o4*4+1] = fmaf(v, w4.y, acc[o4*4+1]);
      acc[o4*4+2] = fmaf(v, w4.z, acc[o4*4+2]);
      acc[o4*4+3] = fmaf(v, w4.w, acc[o4*4+3]);
    }
  }

  float* xb = xout + (size_t)b * CB * HW;
  #pragma unroll
  for (int o = 0; o < CB; ++o) xb[(size_t)o*HW + p] = acc[o];

  const int wv = t >> 6, lane = t & 63;
  #pragma unroll
  for (int o = 0; o < CB; ++o) {
    double a = (double)acc[o], q = a*a;
    for (int off = 32; off; off >>= 1) { a += __shfl_xor(a, off); q += __shfl_xor(q, off); }
    if (lane == 0) { redS[wv][o] = a; redQ[wv][o] = q; }
  }
  __syncthreads();
  if (t < CB) {
    double a = redS[0][t] + redS[1][t] + redS[2][t] + redS[3][t];
    part[(size_t)blk*32 + t] = a;
  } else if (t < 32) {
    int o = t - CB;
    double q = redQ[0][o] + redQ[1][o] + redQ[2][o] + redQ[3][o];
    part[(size_t)blk*32 + t] = q;
  }
}

// ---------------- K1b: finalize BN stats -------------------------------------

__global__ __launch_bounds__(64) void k1b_stats(
    const double* __restrict__ part, const float* __restrict__ gam,
    const float* __restrict__ bet, double* __restrict__ st64, float* __restrict__ st32)
{
  __shared__ double sh[32];
  const int t = threadIdx.x;
  if (t < 32) {
    double a = 0.0;
    #pragma unroll 8
    for (int i = 0; i < 576; ++i) a += part[(size_t)i*32 + t];
    sh[t] = a;
  }
  __syncthreads();
  if (t < CB) {
    const double N = (double)NPIX;
    double mean = sh[t] / N;
    double var  = sh[16+t] / N - mean*mean;
    double rstd = 1.0 / sqrt(var + 1e-5);
    double scl = (double)gam[t] * rstd;
    double sft = (double)bet[t] - mean*scl;
    st64[t] = scl; st64[CB+t] = sft;
    st32[t] = (float)scl; st32[CB+t] = (float)sft;
  }
}

// ---------------- K1c: build split-bf16 B fragments for MFMA -----------------

__global__ __launch_bounds__(256) void k1c_bfrag(
    const float* __restrict__ wm, short* __restrict__ bfrag)
{
  const int t = threadIdx.x;
  for (int e = t; e < 2048; e += 256) {       // (v, ct, lane)
    const int v = e >> 10, ct = (e >> 6) & 15, l = e & 63;
    const int n = l & 15, g = l >> 4;
    const int col = ct*16 + n;
    short out[8];
    #pragma unroll
    for (int j = 0; j < 8; ++j) {
      const int k = g*8 + j;
      const int kk = k & 15;
      const bool hi_half = (k < 16);
      float w = wm[col*CB + kk];
      unsigned short hb = bf16_rne(w);
      float res = w - bf16_tof(hb);
      unsigned short lb = bf16_rne(res);
      bool use_hi = ((v == 0) == hi_half);
      out[j] = (short)(use_hi ? hb : lb);
    }
    bf16x8 pk;
    #pragma unroll
    for (int j = 0; j < 8; ++j) pk[j] = out[j];
    *(bf16x8*)&bfrag[(size_t)e * 8] = pk;
  }
}

// ---------------- K2: fused MFMA (swapped operands) + selection --------------
// 2304 blocks x 256 threads; 64 pixels/block (16 per wave); m fully in regs.

__device__ __forceinline__ void k2_epilogue(int b, int p, int pxl,
    int selN, int nearN, int nselN,
    float* lcw, unsigned char* lidx, unsigned char* lnear,
    unsigned* cidx, float* cw, unsigned* flagcnt, FlagEntry* entries)
{
  int start = selN < 16 ? selN : 16;
  for (int j = start; j < 16; ++j) { lcw[pxl*16 + j] = 0.f; lidx[pxl*16 + j] = 0; }
  unsigned g = (unsigned)(b*HW + p);
  uint4 iv = *(uint4*)&lidx[pxl*16];
  ((uint4*)cidx)[g] = iv;
  float4* cwq = (float4*)cw;
  #pragma unroll
  for (int q = 0; q < 4; ++q) cwq[(size_t)g*4 + q] = *(float4*)&lcw[pxl*16 + q*4];
  bool flag = (nearN > 1) || (selN != 16);
  if (flag) {
    unsigned slot = atomicAdd(flagcnt, 1u);
    FlagEntry e;
    e.pix = g;
    int cnt = nearN < 8 ? nearN : 8;
    e.cnt = (unsigned char)cnt;
    int nsure = selN - nselN;
    int need = 16 - nsure;
    if (need < 0) need = 0;
    if (need > cnt) need = cnt;
    e.need = (unsigned char)need;
    e.r0 = (nearN > 8 || selN != 16) ? 1 : 0;
    e.r1 = 0;
    #pragma unroll
    for (int j = 0; j < 8; ++j) e.ks[j] = (j < cnt) ? lnear[pxl*8 + j] : 0;
    entries[slot] = e;
  }
}

#define PXW 16
#define PXB 64

__global__ __launch_bounds__(256, 3) void k2_main(
    const float* __restrict__ x, const short* __restrict__ bfrag,
    const float* __restrict__ st32, float* __restrict__ msp,
    unsigned* __restrict__ cidx, float* __restrict__ cw,
    unsigned* __restrict__ flagcnt, FlagEntry* __restrict__ entries)
{
  __shared__ short A_st[PXB*40];                        // 5120 B
  __shared__ float lcw[PXB*16];                         // 4096 B
  __shared__ __align__(16) unsigned char lidx[PXB*16];  // 1024 B
  __shared__ unsigned char lnear[PXB*8];                //  512 B

  const int t = threadIdx.x;
  const int blk = blockIdx.x;                           // 2304
  const int b = blk / 576;
  const int p0 = (blk % 576) * PXB;
  const float* xb = x + (size_t)b*CB*HW + p0;

  // ---- phase 0: load x rows, BN+ReLU, split to bf16 hi/lo, stage ----
  #pragma unroll
  for (int r = 0; r < 4; ++r) {
    int e = r*256 + t;
    int o = e >> 6, pl = e & 63;
    float vx = xb[(size_t)o*HW + pl];
    float f = fmaxf(0.f, fmaf(vx, st32[o], st32[CB+o]));
    unsigned short hb = bf16_rne(f);
    float res = f - bf16_tof(hb);
    unsigned short lb = bf16_rne(res);
    A_st[pl*40 + o]      = (short)hb;
    A_st[pl*40 + 16 + o] = (short)lb;
  }
  __syncthreads();

  const int w = t >> 6, l = t & 63;
  const int pl15 = l & 15;            // pixel within wave tile
  const int q = l >> 4;               // quarter (color sub-row / k-chunk)
  const int px = w*PXW + pl15;        // pixel within block
  const int p = p0 + px;              // pixel within image

  // ---- phase 1: MFMA, swapped operands: D[color][pixel] ----
  // feature fragment (B-operand): col = pixel (l&15), k-chunk q*8
  bf16x8 a = *(const bf16x8*)&A_st[px*40 + q*8];
  float mv[64];   // mv[ct*4+i] = m[pixel][ct*16 + q*4 + i]  (static idx!)
  #pragma unroll
  for (int ct = 0; ct < 16; ++ct) {
    bf16x8 b1 = *(const bf16x8*)&bfrag[(size_t)(ct*64 + l)*8];
    bf16x8 b2 = *(const bf16x8*)&bfrag[(size_t)((16 + ct)*64 + l)*8];
    f32x4 acc = {0.f, 0.f, 0.f, 0.f};
    acc = __builtin_amdgcn_mfma_f32_16x16x32_bf16(b1, a, acc, 0, 0, 0);
    acc = __builtin_amdgcn_mfma_f32_16x16x32_bf16(b2, a, acc, 0, 0, 0);
    mv[ct*4+0] = acc[0]; mv[ct*4+1] = acc[1];
    mv[ct*4+2] = acc[2]; mv[ct*4+3] = acc[3];
  }

  // ---- phase 2: streaming top-16; 4 q-lanes per pixel, 64 colors each ----
  float T[16], tmp[16];
  #pragma unroll
  for (int i = 0; i < 16; ++i) tmp[i] = mv[i];
  bitonic16<false>(tmp);
  #pragma unroll
  for (int i = 0; i < 16; ++i) T[i] = tmp[i];
  #pragma unroll
  for (int c = 1; c < 4; ++c) {
    #pragma unroll
    for (int i = 0; i < 16; ++i) tmp[i] = mv[c*16 + i];
    bitonic16<true>(tmp);
    #pragma unroll
    for (int i = 0; i < 16; ++i) T[i] = fmaxf(T[i], tmp[i]);
    bmerge16_desc(T);
  }
  // cross-lane merges among q-partners (lanes pl15 + 16*q'): masks 16, 32
  #pragma unroll
  for (int mk = 16; mk <= 32; mk <<= 1) {
    float R[16];
    #pragma unroll
    for (int i = 0; i < 16; ++i) R[i] = fmaxf(T[i], __shfl_xor(T[15-i], mk));
    bmerge16_desc(R);
    #pragma unroll
    for (int i = 0; i < 16; ++i) T[i] = R[i];
  }
  const float tau = T[15], top = T[0];
  float Z = 0.f;
  #pragma unroll
  for (int i = 0; i < 16; ++i) Z += __expf(T[i] - top);
  const float iZ = 1.f / Z;

  // ---- phase 3a: per-lane counts + 4-lane (q) prefix ----
  int cs = 0, cn = 0, cns = 0;
  #pragma unroll
  for (int j = 0; j < 64; ++j) {
    float v = mv[j];
    bool s = (v >= tau);
    bool nr = (fabsf(v - tau) <= DELTA);
    cs += s ? 1 : 0; cn += nr ? 1 : 0; cns += (s && nr) ? 1 : 0;
  }
  int offs = 0, offn = 0, selN = 0, nearN = 0, nselN = 0;
  #pragma unroll
  for (int q2 = 0; q2 < 4; ++q2) {
    int cv = __shfl(cs,  pl15 + 16*q2);
    int nv = __shfl(cn,  pl15 + 16*q2);
    int sv = __shfl(cns, pl15 + 16*q2);
    selN += cv; nearN += nv; nselN += sv;
    if (q2 < q) { offs += cv; offn += nv; }
  }

  // ---- phase 3b: dense write + compact/near lists (q-major order) ----
  float* mspb = msp + (size_t)b*NCH*HW;
  int isel = 0, inear = 0;
  #pragma unroll
  for (int ct = 0; ct < 16; ++ct) {
    #pragma unroll
    for (int i = 0; i < 4; ++i) {
      const int k = ct*16 + q*4 + i;
      const float v = mv[ct*4+i];
      const bool s = (v >= tau);
      const bool nr = (fabsf(v - tau) <= DELTA);
      float wv = s ? __expf(v - top) * iZ : 0.f;
      mspb[(size_t)k*HW + p] = wv;
      if (s) {
        int slot = offs + isel;
        if (slot < 16) { lcw[px*16 + slot] = wv; lidx[px*16 + slot] = (unsigned char)k; }
        ++isel;
      }
      if (nr) {
        int gs = offn + inear;
        if (gs < 8) lnear[px*8 + gs] = (unsigned char)k;
        ++inear;
      }
    }
  }

  // ---- phase 3c: epilogue (one lane per pixel) ----
  if (q == 0)
    k2_epilogue(b, p, px, selN, nearN, nselN, lcw, lidx, lnear,
                cidx, cw, flagcnt, entries);
}

// ---------------- K2b: wave-cooperative fixup for near-boundary pixels -------
// NOTE: compact lists are NOT assumed k-sorted (k2 emits q-major order).

__global__ __launch_bounds__(64) void k2b_fix(
    const float* __restrict__ bfeat, const float* __restrict__ wb,
    const float* __restrict__ bb, const float* __restrict__ wmg,
    const double* __restrict__ st64,
    const unsigned* __restrict__ flagcnt, const FlagEntry* __restrict__ entries,
    float* __restrict__ msp, unsigned* __restrict__ cidx, float* __restrict__ cw)
{
  __shared__ float wbT[CB][CIN];     // 4 KB: wbT[o][c] = wb[o*CIN+c]
  __shared__ float  wOrigL[16];
  __shared__ int    kOrigL[16];
  __shared__ float  wnL[8];
  __shared__ int    kL[8];
  __shared__ double tvL[16];
  __shared__ int    tiL[16];
  __shared__ float  wvL[16];

  const int lane = threadIdx.x;
  for (int i = lane; i < CB*CIN; i += 64) wbT[i >> 6][i & 63] = wb[i];
  __syncthreads();

  const unsigned n = *flagcnt;
  for (unsigned idx = blockIdx.x; idx < n; idx += gridDim.x) {
    FlagEntry e = entries[idx];
    const int b = (int)(e.pix / HW), p = (int)(e.pix % HW);

    // ---- f64 conv (wave-parallel over channels) + BN + ReLU ----
    const double v = (double)bfeat[(size_t)b*CIN*HW + (size_t)lane*HW + p];
    double ft[CB];
    #pragma unroll
    for (int o = 0; o < CB; ++o) {
      double s = v * (double)wbT[o][lane];
      #pragma unroll
      for (int off = 32; off; off >>= 1) s += __shfl_xor(s, off);
      s += (double)bb[o];
      ft[o] = fmax(0.0, s*st64[o] + st64[CB+o]);
    }

    float* mb = msp + (size_t)b*NCH*HW;
    unsigned char* cb_ = (unsigned char*)cidx + (size_t)e.pix*16;
    float* cwp = cw + (size_t)e.pix*16;

    if (e.r0) {
      // ---- full f64 redo: wave-parallel top-16, (value desc, index asc) ----
      double mm[4]; int kk4[4];
      #pragma unroll
      for (int u = 0; u < 4; ++u) {
        const int k = lane + 64*u; kk4[u] = k;
        const float* wr = wmg + k*CB;
        double a = 0.0;
        #pragma unroll
        for (int c = 0; c < CB; ++c) a = fma(ft[c], (double)wr[c], a);
        mm[u] = a;
      }
      for (int j = 0; j < 16; ++j) {
        double bm = mm[0]; int bk = kk4[0];
        #pragma unroll
        for (int u = 1; u < 4; ++u) {
          bool gt = (mm[u] > bm) || (mm[u] == bm && kk4[u] < bk);
          if (gt) { bm = mm[u]; bk = kk4[u]; }
        }
        #pragma unroll
        for (int off = 32; off; off >>= 1) {
          double om = __shfl_xor(bm, off);
          int ok = __shfl_xor(bk, off);
          bool gt = (om > bm) || (om == bm && ok < bk);
          if (gt) { bm = om; bk = ok; }
        }
        if (lane == 0) { tvL[j] = bm; tiL[j] = bk; }
        #pragma unroll
        for (int u = 0; u < 4; ++u) if (kk4[u] == bk) mm[u] = -1.0e300;
      }
      __syncthreads();
      const double top = tvL[0];
      double ej = (lane < 16) ? exp(tvL[lane] - top) : 0.0;
      double Z = ej;
      #pragma unroll
      for (int off = 32; off; off >>= 1) Z += __shfl_xor(Z, off);
      if (lane < 16) wvL[lane] = (float)(ej / Z);
      __syncthreads();
      int tiR[16]; float wvR[16];
      #pragma unroll
      for (int j = 0; j < 16; ++j) { tiR[j] = tiL[j]; wvR[j] = wvL[j]; }
      #pragma unroll
      for (int u = 0; u < 4; ++u) {
        const int k = lane + 64*u;
        float wv = 0.f;
        #pragma unroll
        for (int j = 0; j < 16; ++j) if (tiR[j] == k) wv = wvR[j];
        mb[(size_t)k*HW + p] = wv;
      }
      if (lane == 0) {
        unsigned used = 0; int on = 0;
        for (int it = 0; it < 16; ++it) {
          int bk = 1 << 20;
          #pragma unroll
          for (int j = 0; j < 16; ++j)
            if (!((used >> j) & 1u) && tiR[j] < bk) bk = tiR[j];
          if (bk >= (1 << 20)) break;
          float bw = 0.f;
          #pragma unroll
          for (int j = 0; j < 16; ++j)
            if (tiR[j] == bk) { bw = wvR[j]; used |= (1u << j); }
          if (bw != 0.f && on < 16) { cb_[on] = (unsigned char)bk; cwp[on] = bw; ++on; }
        }
        for (int j = on; j < 16; ++j) { cb_[j] = 0; cwp[j] = 0.f; }
      }
      __syncthreads();
      continue;
    }

    // ---- light path (selN==16 guaranteed; lane-parallel over near colors) ----
    const int cnt = (e.cnt > 8) ? 8 : (int)e.cnt;
    int need = (int)e.need; if (need > cnt) need = cnt;

    if (lane < 16) { wOrigL[lane] = cwp[lane]; kOrigL[lane] = (int)cb_[lane]; }
    __syncthreads();

    const int myk = (lane < cnt) ? (int)e.ks[lane] : 0x7fffffff;
    double mj = 0.0;
    if (lane < cnt) {
      const float* wr = wmg + myk*CB;
      #pragma unroll
      for (int c = 0; c < CB; ++c) mj = fma(ft[c], (double)wr[c], mj);
    }
    float woldj = 0.f;
    if (lane < cnt) {
      #pragma unroll
      for (int q = 0; q < 16; ++q) {
        if (kOrigL[q] == myk && wOrigL[q] > 0.f) woldj = wOrigL[q];
      }
    }
    // rank among the cnt near colors: (m desc, k asc)
    int rankj = 0;
    #pragma unroll
    for (int j2 = 0; j2 < 8; ++j2) {
      double m2 = __shfl(mj, j2);
      int k2v = __shfl(myk, j2);
      if (lane < cnt && j2 < cnt && j2 != lane) {
        bool gt = (m2 > mj) || (m2 == mj && k2v < myk);
        rankj += gt ? 1 : 0;
      }
    }
    float w2[8];
    #pragma unroll
    for (int j2 = 0; j2 < 8; ++j2) w2[j2] = __shfl(woldj, j2);
    int nw = 0;
    #pragma unroll
    for (int j2 = 0; j2 < 8; ++j2) if (j2 < cnt && w2[j2] > 0.f) ++nw;
    float wnj = 0.f;
    if (lane < cnt && rankj < need && rankj < nw) {
      #pragma unroll
      for (int cand = 0; cand < 8; ++cand) {
        if (cand < cnt && w2[cand] > 0.f) {
          float xv = w2[cand];
          int cgt = 0, cge = 0;
          #pragma unroll
          for (int j2 = 0; j2 < 8; ++j2)
            if (j2 < cnt && w2[j2] > 0.f) { cgt += (w2[j2] > xv); cge += (w2[j2] >= xv); }
          if (cgt <= rankj && rankj < cge) wnj = xv;
        }
      }
    }
    if (lane < cnt) mb[(size_t)myk*HW + p] = wnj;   // dense updates
    if (lane < 8)  { wnL[lane] = wnj; kL[lane] = myk; }
    __syncthreads();

    if (lane == 0) {
      // order-insensitive rebuild: originals (minus near-set) + updated near
      unsigned char nk[16]; float nwv[16];
      int on = 0;
      for (int j = 0; j < 16; ++j) {
        int ko = kOrigL[j]; float wo = wOrigL[j];
        if (wo <= 0.f) continue;
        bool isNear = false;
        #pragma unroll
        for (int j2 = 0; j2 < 8; ++j2)
          if (j2 < cnt && kL[j2] == ko) isNear = true;
        if (isNear) continue;
        if (on < 16) { nk[on] = (unsigned char)ko; nwv[on] = wo; ++on; }
      }
      for (int j2 = 0; j2 < 8; ++j2)
        if (j2 < cnt && wnL[j2] > 0.f && on < 16) {
          nk[on] = (unsigned char)kL[j2]; nwv[on] = wnL[j2]; ++on;
        }
      for (int j = 0; j < on; ++j) { cb_[j] = nk[j]; cwp[j] = nwv[j]; }
      for (int j = on; j < 16; ++j) { cb_[j] = 0; cwp[j] = 0.f; }
    }
    __syncthreads();
  }
}

// ---------------- K3: num/den accumulation -----------------------------------

__global__ __launch_bounds__(256) void k3_accum(
    const uint4* __restrict__ cidx, const float4* __restrict__ cw4,
    const float* __restrict__ img, float* __restrict__ part)
{
  __shared__ float acc[1024];
  const int t = threadIdx.x, blk = blockIdx.x;
  for (int i = t; i < 1024; i += 256) acc[i] = 0.f;
  __syncthreads();
  const int b = blk / 144;
  const int p = (blk % 144) * 256 + t;
  const float* imb = img + (size_t)b*3*HW;
  const int g = b*HW + p;
  uint4 iv = cidx[g];
  unsigned ivq[4] = {iv.x, iv.y, iv.z, iv.w};
  float r = imb[p], g_ = imb[HW + p], bl = imb[2*HW + p];
  #pragma unroll
  for (int q = 0; q < 4; ++q) {
    float4 wv = cw4[(size_t)g*4 + q];
    float wvv[4] = {wv.x, wv.y, wv.z, wv.w};
    #pragma unroll
    for (int u = 0; u < 4; ++u) {
      int k = (int)((ivq[q] >> (8*u)) & 255u);
      float wgt = wvv[u];
      atomicAdd(&acc[k],       wgt * r);
      atomicAdd(&acc[256 + k], wgt * g_);
      atomicAdd(&acc[512 + k], wgt * bl);
      atomicAdd(&acc[768 + k], wgt);
    }
  }
  __syncthreads();
  for (int i = t; i < 1024; i += 256) part[(size_t)blk*1024 + i] = acc[i];
}

// ---------------- K4: palette ------------------------------------------------

__global__ __launch_bounds__(256) void k4_pal(
    const float* __restrict__ part, float* __restrict__ out_pal)
{
  __shared__ float acc[1024];
  const int b = blockIdx.x, t = threadIdx.x;
  for (int s = t; s < 1024; s += 256) {
    float a = 0.f;
    for (int i = 0; i < 144; ++i) a += part[(size_t)(b*144 + i)*1024 + s];
    acc[s] = a;
  }
  __syncthreads();
  for (int s = t; s < 768; s += 256) {
    int k = s & 255;
    float den = acc[768 + k] + 1e-8f;
    out_pal[(size_t)b*768 + s] = acc[s] / den;
  }
}

// ---------------- K5: recolored image ----------------------------------------

__global__ __launch_bounds__(256) void k5_img(
    const uint4* __restrict__ cidx, const float4* __restrict__ cw4,
    const float* __restrict__ pal, float* __restrict__ outimg)
{
  __shared__ float lp[768];
  const int t = threadIdx.x, blk = blockIdx.x;
  const int b = blk / 144;
  for (int i = t; i < 768; i += 256) lp[i] = pal[(size_t)b*768 + i];
  __syncthreads();
  const int p = (blk % 144) * 256 + t;
  const int g = b*HW + p;
  uint4 iv = cidx[g];
  unsigned ivq[4] = {iv.x, iv.y, iv.z, iv.w};
  float r = 0.f, g_ = 0.f, bl = 0.f;
  #pragma unroll
  for (int q = 0; q < 4; ++q) {
    float4 wv = cw4[(size_t)g*4 + q];
    float wvv[4] = {wv.x, wv.y, wv.z, wv.w};
    #pragma unroll
    for (int u = 0; u < 4; ++u) {
      int k = (int)((ivq[q] >> (8*u)) & 255u);
      float wgt = wvv[u];
      r  = fmaf(wgt, lp[k],       r);
      g_ = fmaf(wgt, lp[256 + k], g_);
      bl = fmaf(wgt, lp[512 + k], bl);
    }
  }
  float* ob = outimg + (size_t)b*3*HW;
  ob[p] = r; ob[HW + p] = g_; ob[2*HW + p] = bl;
}

// ---------------- launcher ---------------------------------------------------

extern "C" void kernel_launch(void* const* d_in, const int* in_sizes, int n_in,
                              void* d_out, int out_size, void* d_ws, size_t ws_size,
                              hipStream_t stream)
{
  const float* img   = (const float*)d_in[0];
  const float* bfeat = (const float*)d_in[1];
  const float* wb    = (const float*)d_in[2];
  const float* bb    = (const float*)d_in[3];
  const float* gam   = (const float*)d_in[4];
  const float* bet   = (const float*)d_in[5];
  const float* wm    = (const float*)d_in[6];

  float* out_img = (float*)d_out;                 // [4,3,192,192]
  float* out_msp = (float*)d_out + 442368;        // [4,256,192,192]
  float* out_pal = (float*)d_out + 38191104;      // [4,3,256,1,1]

  char* w = (char*)d_ws;
  float*     ws_x       = (float*)(w);                     // 9,437,184 B (dead after k2 -> reused for k3 partials)
  double*    ws_part    = (double*)(w + 9437184);          //   147,456 B
  double*    ws_st64    = (double*)(w + 9584640);          //       256 B
  float*     ws_st32    = (float*)(w + 9584896);           //       128 B
  unsigned*  ws_flagcnt = (unsigned*)(w + 9585152);        //       256 B pad
  FlagEntry* ws_entries = (FlagEntry*)(w + 9585408);       // 2,359,296 B
  unsigned*  ws_cidx    = (unsigned*)(w + 11944704);       // 2,359,296 B
  float*     ws_cw      = (float*)(w + 14304000);          // 9,437,184 B
  float*     ws_nd      = ws_x;                            // aliases ws_x (x dead after k2)
  short*     ws_bfrag   = (short*)(w + 23741184);          //    32,768 B

  k0_zero<<<dim3(1), dim3(1), 0, stream>>>(ws_flagcnt);
  k1_conv<<<dim3(576), dim3(256), 0, stream>>>(bfeat, wb, bb, ws_x, ws_part);
  k1b_stats<<<dim3(1), dim3(64), 0, stream>>>(ws_part, gam, bet, ws_st64, ws_st32);
  k1c_bfrag<<<dim3(1), dim3(256), 0, stream>>>(wm, ws_bfrag);
  k2_main<<<dim3(2304), dim3(256), 0, stream>>>(ws_x, ws_bfrag, ws_st32, out_msp,
                                                ws_cidx, ws_cw, ws_flagcnt, ws_entries);
  k2b_fix<<<dim3(4096), dim3(64), 0, stream>>>(bfeat, wb, bb, wm, ws_st64,
                                               ws_flagcnt, ws_entries, out_msp, ws_cidx, ws_cw);
  k3_accum<<<dim3(576), dim3(256), 0, stream>>>((const uint4*)ws_cidx, (const float4*)ws_cw,
                                                img, ws_nd);
  k4_pal<<<dim3(4), dim3(256), 0, stream>>>(ws_nd, out_pal);
  k5_img<<<dim3(576), dim3(256), 0, stream>>>((const uint4*)ws_cidx, (const float4*)ws_cw,
                                              out_pal, out_img);
}

// Round 11
// 261.819 us; speedup vs baseline: 1.7078x; 1.1361x over previous
//
#include <hip/hip_runtime.h>

#define HW    36864
#define NB    4
#define NCH   256
#define CIN   64
#define CB    16
#define NPIX  (NB*HW)          // 147456
#define DELTA 1e-4f

typedef short bf16x8 __attribute__((ext_vector_type(8)));
typedef float f32x4  __attribute__((ext_vector_type(4)));

struct FlagEntry {
  unsigned pix;
  unsigned char cnt, need, r0, r1;   // r0 = full-f64-redo flag
  unsigned char ks[8];
};                              // 16 B

// ---------------- bf16 split helpers (RNE) -----------------------------------

__device__ __forceinline__ unsigned short bf16_rne(float x) {
  unsigned u = __float_as_uint(x);
  unsigned r = u + 0x7fffu + ((u >> 16) & 1u);
  return (unsigned short)(r >> 16);
}
__device__ __forceinline__ float bf16_tof(unsigned short h) {
  return __uint_as_float(((unsigned)h) << 16);
}

// ---------------- sorting networks (values only, fully unrolled) -------------

template<bool ASC>
__device__ __forceinline__ void bitonic16(float* v) {
  #pragma unroll
  for (int K = 2; K <= 16; K <<= 1) {
    #pragma unroll
    for (int J = K >> 1; J > 0; J >>= 1) {
      #pragma unroll
      for (int i = 0; i < 16; ++i) {
        int l = i ^ J;
        if (l > i) {
          bool up = (((i & K) == 0) == ASC);
          float a = v[i], b = v[l];
          float lo = fminf(a, b), hi = fmaxf(a, b);
          v[i] = up ? lo : hi;
          v[l] = up ? hi : lo;
        }
      }
    }
  }
}

__device__ __forceinline__ void bmerge16_desc(float* v) {
  #pragma unroll
  for (int J = 8; J > 0; J >>= 1) {
    #pragma unroll
    for (int i = 0; i < 16; ++i) {
      int l = i ^ J;
      if (l > i) {
        float a = v[i], b = v[l];
        float lo = fminf(a, b), hi = fmaxf(a, b);
        v[i] = hi; v[l] = lo;
      }
    }
  }
}

// ---------------- K1: 1x1 conv (64->16) + f64 stats partials -----------------

__global__ __launch_bounds__(256) void k1_conv(
    const float* __restrict__ bfeat, const float* __restrict__ wb,
    const float* __restrict__ bb, float* __restrict__ xout,
    double* __restrict__ part)
{
  __shared__ float wbT[CIN][CB];          // 4 KB
  __shared__ double redS[4][CB];
  __shared__ double redQ[4][CB];
  const int t = threadIdx.x;
  for (int i = t; i < CIN*CB; i += 256) {
    int o = i >> 6, c = i & 63;
    wbT[c][o] = wb[i];
  }
  __syncthreads();

  const int blk = blockIdx.x;             // 576
  const int b = blk / 144, seg = blk % 144;
  const int p = seg * 256 + t;
  const float* bfb = bfeat + (size_t)b * CIN * HW;

  float acc[CB];
  #pragma unroll
  for (int o = 0; o < CB; ++o) acc[o] = bb[o];

  for (int c = 0; c < CIN; ++c) {
    float v = bfb[(size_t)c*HW + p];
    #pragma unroll
    for (int o4 = 0; o4 < 4; ++o4) {
      float4 w4 = *(const float4*)&wbT[c][o4*4];
      acc[o4*4+0] = fmaf(v, w4.x, acc[o4*4+0]);
      acc[o4*4+1] = fmaf(v, w4.y, acc[o4*4+1]);
      acc[o4*4+2] = fmaf(v, w4.z, acc[o4*4+2]);
      acc[o4*4+3] = fmaf(v, w4.w, acc[o4*4+3]);
    }
  }

  float* xb = xout + (size_t)b * CB * HW;
  #pragma unroll
  for (int o = 0; o < CB; ++o) xb[(size_t)o*HW + p] = acc[o];

  const int wv = t >> 6, lane = t & 63;
  #pragma unroll
  for (int o = 0; o < CB; ++o) {
    double a = (double)acc[o], q = a*a;
    for (int off = 32; off; off >>= 1) { a += __shfl_xor(a, off); q += __shfl_xor(q, off); }
    if (lane == 0) { redS[wv][o] = a; redQ[wv][o] = q; }
  }
  __syncthreads();
  if (t < CB) {
    double a = redS[0][t] + redS[1][t] + redS[2][t] + redS[3][t];
    part[(size_t)blk*32 + t] = a;
  } else if (t < 32) {
    int o = t - CB;
    double q = redQ[0][o] + redQ[1][o] + redQ[2][o] + redQ[3][o];
    part[(size_t)blk*32 + t] = q;
  }
}

// ---------------- K1x: merged aux (stats+flagzero | bfrag) -------------------
// grid 2 x 256. Block 0: parallel stats reduce + st64/st32 + zero flagcnt.
// Block 1: split-bf16 B fragments.

__global__ __launch_bounds__(256) void k1x_aux(
    const double* __restrict__ part, const float* __restrict__ gam,
    const float* __restrict__ bet, double* __restrict__ st64,
    float* __restrict__ st32, const float* __restrict__ wm,
    short* __restrict__ bfrag, unsigned* __restrict__ flagcnt)
{
  const int t = threadIdx.x;
  if (blockIdx.x == 0) {
    if (t == 0) *flagcnt = 0u;
    __shared__ double red[8][32];
    const int g = t >> 5, ch = t & 31;
    double a = 0.0;
    #pragma unroll 8
    for (int i = g; i < 576; i += 8) a += part[(size_t)i*32 + ch];
    red[g][ch] = a;
    __syncthreads();
    if (t < 32) {
      double s = 0.0;
      #pragma unroll
      for (int g2 = 0; g2 < 8; ++g2) s += red[g2][t];
      red[0][t] = s;
    }
    __syncthreads();
    if (t < CB) {
      const double N = (double)NPIX;
      double mean = red[0][t] / N;
      double var  = red[0][16+t] / N - mean*mean;
      double rstd = 1.0 / sqrt(var + 1e-5);
      double scl = (double)gam[t] * rstd;
      double sft = (double)bet[t] - mean*scl;
      st64[t] = scl; st64[CB+t] = sft;
      st32[t] = (float)scl; st32[CB+t] = (float)sft;
    }
  } else {
    for (int e = t; e < 2048; e += 256) {       // (v, ct, lane)
      const int v = e >> 10, ct = (e >> 6) & 15, l = e & 63;
      const int n = l & 15, g = l >> 4;
      const int col = ct*16 + n;
      short out[8];
      #pragma unroll
      for (int j = 0; j < 8; ++j) {
        const int k = g*8 + j;
        const int kk = k & 15;
        const bool hi_half = (k < 16);
        float w = wm[col*CB + kk];
        unsigned short hb = bf16_rne(w);
        float res = w - bf16_tof(hb);
        unsigned short lb = bf16_rne(res);
        bool use_hi = ((v == 0) == hi_half);
        out[j] = (short)(use_hi ? hb : lb);
      }
      bf16x8 pk;
      #pragma unroll
      for (int j = 0; j < 8; ++j) pk[j] = out[j];
      *(bf16x8*)&bfrag[(size_t)e * 8] = pk;
    }
  }
}

// ---------------- K2: fused MFMA (swapped operands) + selection --------------
// 2304 blocks x 256 threads; 64 pixels/block (16 per wave); m fully in regs.

__device__ __forceinline__ void k2_epilogue(int b, int p, int pxl,
    int selN, int nearN, int nselN,
    float* lcw, unsigned char* lidx, unsigned char* lnear,
    unsigned* cidx, float* cw, unsigned* flagcnt, FlagEntry* entries)
{
  int start = selN < 16 ? selN : 16;
  for (int j = start; j < 16; ++j) { lcw[pxl*16 + j] = 0.f; lidx[pxl*16 + j] = 0; }
  unsigned g = (unsigned)(b*HW + p);
  uint4 iv = *(uint4*)&lidx[pxl*16];
  ((uint4*)cidx)[g] = iv;
  float4* cwq = (float4*)cw;
  #pragma unroll
  for (int q = 0; q < 4; ++q) cwq[(size_t)g*4 + q] = *(float4*)&lcw[pxl*16 + q*4];
  bool flag = (nearN > 1) || (selN != 16);
  if (flag) {
    unsigned slot = atomicAdd(flagcnt, 1u);
    FlagEntry e;
    e.pix = g;
    int cnt = nearN < 8 ? nearN : 8;
    e.cnt = (unsigned char)cnt;
    int nsure = selN - nselN;
    int need = 16 - nsure;
    if (need < 0) need = 0;
    if (need > cnt) need = cnt;
    e.need = (unsigned char)need;
    e.r0 = (nearN > 8 || selN != 16) ? 1 : 0;
    e.r1 = 0;
    #pragma unroll
    for (int j = 0; j < 8; ++j) e.ks[j] = (j < cnt) ? lnear[pxl*8 + j] : 0;
    entries[slot] = e;
  }
}

#define PXW 16
#define PXB 64

__global__ __launch_bounds__(256, 3) void k2_main(
    const float* __restrict__ x, const short* __restrict__ bfrag,
    const float* __restrict__ st32, float* __restrict__ msp,
    unsigned* __restrict__ cidx, float* __restrict__ cw,
    unsigned* __restrict__ flagcnt, FlagEntry* __restrict__ entries)
{
  __shared__ short A_st[PXB*40];                        // 5120 B
  __shared__ float lcw[PXB*16];                         // 4096 B
  __shared__ __align__(16) unsigned char lidx[PXB*16];  // 1024 B
  __shared__ unsigned char lnear[PXB*8];                //  512 B

  const int t = threadIdx.x;
  const int blk = blockIdx.x;                           // 2304
  const int b = blk / 576;
  const int p0 = (blk % 576) * PXB;
  const float* xb = x + (size_t)b*CB*HW + p0;

  // ---- phase 0: load x rows, BN+ReLU, split to bf16 hi/lo, stage ----
  #pragma unroll
  for (int r = 0; r < 4; ++r) {
    int e = r*256 + t;
    int o = e >> 6, pl = e & 63;
    float vx = xb[(size_t)o*HW + pl];
    float f = fmaxf(0.f, fmaf(vx, st32[o], st32[CB+o]));
    unsigned short hb = bf16_rne(f);
    float res = f - bf16_tof(hb);
    unsigned short lb = bf16_rne(res);
    A_st[pl*40 + o]      = (short)hb;
    A_st[pl*40 + 16 + o] = (short)lb;
  }
  __syncthreads();

  const int w = t >> 6, l = t & 63;
  const int pl15 = l & 15;            // pixel within wave tile
  const int q = l >> 4;               // quarter (color sub-row / k-chunk)
  const int px = w*PXW + pl15;        // pixel within block
  const int p = p0 + px;              // pixel within image

  // ---- phase 1: MFMA, swapped operands: D[color][pixel] ----
  bf16x8 a = *(const bf16x8*)&A_st[px*40 + q*8];
  float mv[64];   // mv[ct*4+i] = m[pixel][ct*16 + q*4 + i]  (static idx!)
  #pragma unroll
  for (int ct = 0; ct < 16; ++ct) {
    bf16x8 b1 = *(const bf16x8*)&bfrag[(size_t)(ct*64 + l)*8];
    bf16x8 b2 = *(const bf16x8*)&bfrag[(size_t)((16 + ct)*64 + l)*8];
    f32x4 acc = {0.f, 0.f, 0.f, 0.f};
    acc = __builtin_amdgcn_mfma_f32_16x16x32_bf16(b1, a, acc, 0, 0, 0);
    acc = __builtin_amdgcn_mfma_f32_16x16x32_bf16(b2, a, acc, 0, 0, 0);
    mv[ct*4+0] = acc[0]; mv[ct*4+1] = acc[1];
    mv[ct*4+2] = acc[2]; mv[ct*4+3] = acc[3];
  }

  // ---- phase 2: streaming top-16; 4 q-lanes per pixel, 64 colors each ----
  float T[16], tmp[16];
  #pragma unroll
  for (int i = 0; i < 16; ++i) tmp[i] = mv[i];
  bitonic16<false>(tmp);
  #pragma unroll
  for (int i = 0; i < 16; ++i) T[i] = tmp[i];
  #pragma unroll
  for (int c = 1; c < 4; ++c) {
    #pragma unroll
    for (int i = 0; i < 16; ++i) tmp[i] = mv[c*16 + i];
    bitonic16<true>(tmp);
    #pragma unroll
    for (int i = 0; i < 16; ++i) T[i] = fmaxf(T[i], tmp[i]);
    bmerge16_desc(T);
  }
  // cross-lane merges among q-partners (lanes pl15 + 16*q'): masks 16, 32
  #pragma unroll
  for (int mk = 16; mk <= 32; mk <<= 1) {
    float R[16];
    #pragma unroll
    for (int i = 0; i < 16; ++i) R[i] = fmaxf(T[i], __shfl_xor(T[15-i], mk));
    bmerge16_desc(R);
    #pragma unroll
    for (int i = 0; i < 16; ++i) T[i] = R[i];
  }
  const float tau = T[15], top = T[0];
  float Z = 0.f;
  #pragma unroll
  for (int i = 0; i < 16; ++i) Z += __expf(T[i] - top);
  const float iZ = 1.f / Z;

  // ---- phase 3a: per-lane counts + 4-lane (q) prefix ----
  int cs = 0, cn = 0, cns = 0;
  #pragma unroll
  for (int j = 0; j < 64; ++j) {
    float v = mv[j];
    bool s = (v >= tau);
    bool nr = (fabsf(v - tau) <= DELTA);
    cs += s ? 1 : 0; cn += nr ? 1 : 0; cns += (s && nr) ? 1 : 0;
  }
  int offs = 0, offn = 0, selN = 0, nearN = 0, nselN = 0;
  #pragma unroll
  for (int q2 = 0; q2 < 4; ++q2) {
    int cv = __shfl(cs,  pl15 + 16*q2);
    int nv = __shfl(cn,  pl15 + 16*q2);
    int sv = __shfl(cns, pl15 + 16*q2);
    selN += cv; nearN += nv; nselN += sv;
    if (q2 < q) { offs += cv; offn += nv; }
  }

  // ---- phase 3b: dense write + compact/near lists (q-major order) ----
  float* mspb = msp + (size_t)b*NCH*HW;
  int isel = 0, inear = 0;
  #pragma unroll
  for (int ct = 0; ct < 16; ++ct) {
    #pragma unroll
    for (int i = 0; i < 4; ++i) {
      const int k = ct*16 + q*4 + i;
      const float v = mv[ct*4+i];
      const bool s = (v >= tau);
      const bool nr = (fabsf(v - tau) <= DELTA);
      float wv = s ? __expf(v - top) * iZ : 0.f;
      mspb[(size_t)k*HW + p] = wv;
      if (s) {
        int slot = offs + isel;
        if (slot < 16) { lcw[px*16 + slot] = wv; lidx[px*16 + slot] = (unsigned char)k; }
        ++isel;
      }
      if (nr) {
        int gs = offn + inear;
        if (gs < 8) lnear[px*8 + gs] = (unsigned char)k;
        ++inear;
      }
    }
  }

  // ---- phase 3c: epilogue (one lane per pixel) ----
  if (q == 0)
    k2_epilogue(b, p, px, selN, nearN, nselN, lcw, lidx, lnear,
                cidx, cw, flagcnt, entries);
}

// ---------------- K2b: wave-cooperative fixup for near-boundary pixels -------
// NOTE: compact lists are NOT assumed k-sorted (k2 emits q-major order).

__global__ __launch_bounds__(64) void k2b_fix(
    const float* __restrict__ bfeat, const float* __restrict__ wb,
    const float* __restrict__ bb, const float* __restrict__ wmg,
    const double* __restrict__ st64,
    const unsigned* __restrict__ flagcnt, const FlagEntry* __restrict__ entries,
    float* __restrict__ msp, unsigned* __restrict__ cidx, float* __restrict__ cw)
{
  __shared__ float wbT[CB][CIN];     // 4 KB: wbT[o][c] = wb[o*CIN+c]
  __shared__ float  wOrigL[16];
  __shared__ int    kOrigL[16];
  __shared__ float  wnL[8];
  __shared__ int    kL[8];
  __shared__ double tvL[16];
  __shared__ int    tiL[16];
  __shared__ float  wvL[16];

  const int lane = threadIdx.x;
  for (int i = lane; i < CB*CIN; i += 64) wbT[i >> 6][i & 63] = wb[i];
  __syncthreads();

  const unsigned n = *flagcnt;
  for (unsigned idx = blockIdx.x; idx < n; idx += gridDim.x) {
    FlagEntry e = entries[idx];
    const int b = (int)(e.pix / HW), p = (int)(e.pix % HW);

    // ---- f64 conv (wave-parallel over channels) + BN + ReLU ----
    const double v = (double)bfeat[(size_t)b*CIN*HW + (size_t)lane*HW + p];
    double ft[CB];
    #pragma unroll
    for (int o = 0; o < CB; ++o) {
      double s = v * (double)wbT[o][lane];
      #pragma unroll
      for (int off = 32; off; off >>= 1) s += __shfl_xor(s, off);
      s += (double)bb[o];
      ft[o] = fmax(0.0, s*st64[o] + st64[CB+o]);
    }

    float* mb = msp + (size_t)b*NCH*HW;
    unsigned char* cb_ = (unsigned char*)cidx + (size_t)e.pix*16;
    float* cwp = cw + (size_t)e.pix*16;

    if (e.r0) {
      // ---- full f64 redo: wave-parallel top-16, (value desc, index asc) ----
      double mm[4]; int kk4[4];
      #pragma unroll
      for (int u = 0; u < 4; ++u) {
        const int k = lane + 64*u; kk4[u] = k;
        const float* wr = wmg + k*CB;
        double a = 0.0;
        #pragma unroll
        for (int c = 0; c < CB; ++c) a = fma(ft[c], (double)wr[c], a);
        mm[u] = a;
      }
      for (int j = 0; j < 16; ++j) {
        double bm = mm[0]; int bk = kk4[0];
        #pragma unroll
        for (int u = 1; u < 4; ++u) {
          bool gt = (mm[u] > bm) || (mm[u] == bm && kk4[u] < bk);
          if (gt) { bm = mm[u]; bk = kk4[u]; }
        }
        #pragma unroll
        for (int off = 32; off; off >>= 1) {
          double om = __shfl_xor(bm, off);
          int ok = __shfl_xor(bk, off);
          bool gt = (om > bm) || (om == bm && ok < bk);
          if (gt) { bm = om; bk = ok; }
        }
        if (lane == 0) { tvL[j] = bm; tiL[j] = bk; }
        #pragma unroll
        for (int u = 0; u < 4; ++u) if (kk4[u] == bk) mm[u] = -1.0e300;
      }
      __syncthreads();
      const double top = tvL[0];
      double ej = (lane < 16) ? exp(tvL[lane] - top) : 0.0;
      double Z = ej;
      #pragma unroll
      for (int off = 32; off; off >>= 1) Z += __shfl_xor(Z, off);
      if (lane < 16) wvL[lane] = (float)(ej / Z);
      __syncthreads();
      int tiR[16]; float wvR[16];
      #pragma unroll
      for (int j = 0; j < 16; ++j) { tiR[j] = tiL[j]; wvR[j] = wvL[j]; }
      #pragma unroll
      for (int u = 0; u < 4; ++u) {
        const int k = lane + 64*u;
        float wv = 0.f;
        #pragma unroll
        for (int j = 0; j < 16; ++j) if (tiR[j] == k) wv = wvR[j];
        mb[(size_t)k*HW + p] = wv;
      }
      if (lane == 0) {
        unsigned used = 0; int on = 0;
        for (int it = 0; it < 16; ++it) {
          int bk = 1 << 20;
          #pragma unroll
          for (int j = 0; j < 16; ++j)
            if (!((used >> j) & 1u) && tiR[j] < bk) bk = tiR[j];
          if (bk >= (1 << 20)) break;
          float bw = 0.f;
          #pragma unroll
          for (int j = 0; j < 16; ++j)
            if (tiR[j] == bk) { bw = wvR[j]; used |= (1u << j); }
          if (bw != 0.f && on < 16) { cb_[on] = (unsigned char)bk; cwp[on] = bw; ++on; }
        }
        for (int j = on; j < 16; ++j) { cb_[j] = 0; cwp[j] = 0.f; }
      }
      __syncthreads();
      continue;
    }

    // ---- light path (selN==16 guaranteed; lane-parallel over near colors) ----
    const int cnt = (e.cnt > 8) ? 8 : (int)e.cnt;
    int need = (int)e.need; if (need > cnt) need = cnt;

    if (lane < 16) { wOrigL[lane] = cwp[lane]; kOrigL[lane] = (int)cb_[lane]; }
    __syncthreads();

    const int myk = (lane < cnt) ? (int)e.ks[lane] : 0x7fffffff;
    double mj = 0.0;
    if (lane < cnt) {
      const float* wr = wmg + myk*CB;
      #pragma unroll
      for (int c = 0; c < CB; ++c) mj = fma(ft[c], (double)wr[c], mj);
    }
    float woldj = 0.f;
    if (lane < cnt) {
      #pragma unroll
      for (int q = 0; q < 16; ++q) {
        if (kOrigL[q] == myk && wOrigL[q] > 0.f) woldj = wOrigL[q];
      }
    }
    // rank among the cnt near colors: (m desc, k asc)
    int rankj = 0;
    #pragma unroll
    for (int j2 = 0; j2 < 8; ++j2) {
      double m2 = __shfl(mj, j2);
      int k2v = __shfl(myk, j2);
      if (lane < cnt && j2 < cnt && j2 != lane) {
        bool gt = (m2 > mj) || (m2 == mj && k2v < myk);
        rankj += gt ? 1 : 0;
      }
    }
    float w2[8];
    #pragma unroll
    for (int j2 = 0; j2 < 8; ++j2) w2[j2] = __shfl(woldj, j2);
    int nw = 0;
    #pragma unroll
    for (int j2 = 0; j2 < 8; ++j2) if (j2 < cnt && w2[j2] > 0.f) ++nw;
    float wnj = 0.f;
    if (lane < cnt && rankj < need && rankj < nw) {
      #pragma unroll
      for (int cand = 0; cand < 8; ++cand) {
        if (cand < cnt && w2[cand] > 0.f) {
          float xv = w2[cand];
          int cgt = 0, cge = 0;
          #pragma unroll
          for (int j2 = 0; j2 < 8; ++j2)
            if (j2 < cnt && w2[j2] > 0.f) { cgt += (w2[j2] > xv); cge += (w2[j2] >= xv); }
          if (cgt <= rankj && rankj < cge) wnj = xv;
        }
      }
    }
    if (lane < cnt) mb[(size_t)myk*HW + p] = wnj;   // dense updates
    if (lane < 8)  { wnL[lane] = wnj; kL[lane] = myk; }
    __syncthreads();

    if (lane == 0) {
      // order-insensitive rebuild: originals (minus near-set) + updated near
      unsigned char nk[16]; float nwv[16];
      int on = 0;
      for (int j = 0; j < 16; ++j) {
        int ko = kOrigL[j]; float wo = wOrigL[j];
        if (wo <= 0.f) continue;
        bool isNear = false;
        #pragma unroll
        for (int j2 = 0; j2 < 8; ++j2)
          if (j2 < cnt && kL[j2] == ko) isNear = true;
        if (isNear) continue;
        if (on < 16) { nk[on] = (unsigned char)ko; nwv[on] = wo; ++on; }
      }
      for (int j2 = 0; j2 < 8; ++j2)
        if (j2 < cnt && wnL[j2] > 0.f && on < 16) {
          nk[on] = (unsigned char)kL[j2]; nwv[on] = wnL[j2]; ++on;
        }
      for (int j = 0; j < on; ++j) { cb_[j] = nk[j]; cwp[j] = nwv[j]; }
      for (int j = on; j < 16; ++j) { cb_[j] = 0; cwp[j] = 0.f; }
    }
    __syncthreads();
  }
}

// ---------------- K3: num/den accumulation (per-wave private histograms) -----

__global__ __launch_bounds__(256) void k3_accum(
    const uint4* __restrict__ cidx, const float4* __restrict__ cw4,
    const float* __restrict__ img, float* __restrict__ part)
{
  __shared__ float acc[4][1024];     // 16 KB, one histogram per wave
  const int t = threadIdx.x, blk = blockIdx.x;
  for (int i = t; i < 4096; i += 256) ((float*)acc)[i] = 0.f;
  __syncthreads();
  const int wv = t >> 6;
  const int b = blk / 144;
  const int p = (blk % 144) * 256 + t;
  const float* imb = img + (size_t)b*3*HW;
  const int g = b*HW + p;
  uint4 iv = cidx[g];
  unsigned ivq[4] = {iv.x, iv.y, iv.z, iv.w};
  float r = imb[p], g_ = imb[HW + p], bl = imb[2*HW + p];
  #pragma unroll
  for (int q = 0; q < 4; ++q) {
    float4 wvv4 = cw4[(size_t)g*4 + q];
    float wvv[4] = {wvv4.x, wvv4.y, wvv4.z, wvv4.w};
    #pragma unroll
    for (int u = 0; u < 4; ++u) {
      int k = (int)((ivq[q] >> (8*u)) & 255u);
      float wgt = wvv[u];
      atomicAdd(&acc[wv][k],       wgt * r);
      atomicAdd(&acc[wv][256 + k], wgt * g_);
      atomicAdd(&acc[wv][512 + k], wgt * bl);
      atomicAdd(&acc[wv][768 + k], wgt);
    }
  }
  __syncthreads();
  for (int i = t; i < 1024; i += 256)
    part[(size_t)blk*1024 + i] = (acc[0][i] + acc[1][i]) + (acc[2][i] + acc[3][i]);
}

// ---------------- K4: palette (register-only reduction) ----------------------

__global__ __launch_bounds__(256) void k4_pal(
    const float* __restrict__ part, float* __restrict__ out_pal)
{
  const int b = blockIdx.x, t = threadIdx.x;   // grid 4 x 256
  float ar = 0.f, ag = 0.f, ab = 0.f, aw = 0.f;
  for (int i = 0; i < 144; ++i) {
    const float* pp = part + (size_t)(b*144 + i)*1024;
    ar += pp[t]; ag += pp[256 + t]; ab += pp[512 + t]; aw += pp[768 + t];
  }
  float den = aw + 1e-8f;
  out_pal[(size_t)b*768 + t]       = ar / den;
  out_pal[(size_t)b*768 + 256 + t] = ag / den;
  out_pal[(size_t)b*768 + 512 + t] = ab / den;
}

// ---------------- K5: recolored image ----------------------------------------

__global__ __launch_bounds__(256) void k5_img(
    const uint4* __restrict__ cidx, const float4* __restrict__ cw4,
    const float* __restrict__ pal, float* __restrict__ outimg)
{
  __shared__ float lp[768];
  const int t = threadIdx.x, blk = blockIdx.x;
  const int b = blk / 144;
  for (int i = t; i < 768; i += 256) lp[i] = pal[(size_t)b*768 + i];
  __syncthreads();
  const int p = (blk % 144) * 256 + t;
  const int g = b*HW + p;
  uint4 iv = cidx[g];
  unsigned ivq[4] = {iv.x, iv.y, iv.z, iv.w};
  float r = 0.f, g_ = 0.f, bl = 0.f;
  #pragma unroll
  for (int q = 0; q < 4; ++q) {
    float4 wv = cw4[(size_t)g*4 + q];
    float wvv[4] = {wv.x, wv.y, wv.z, wv.w};
    #pragma unroll
    for (int u = 0; u < 4; ++u) {
      int k = (int)((ivq[q] >> (8*u)) & 255u);
      float wgt = wvv[u];
      r  = fmaf(wgt, lp[k],       r);
      g_ = fmaf(wgt, lp[256 + k], g_);
      bl = fmaf(wgt, lp[512 + k], bl);
    }
  }
  float* ob = outimg + (size_t)b*3*HW;
  ob[p] = r; ob[HW + p] = g_; ob[2*HW + p] = bl;
}

// ---------------- launcher ---------------------------------------------------

extern "C" void kernel_launch(void* const* d_in, const int* in_sizes, int n_in,
                              void* d_out, int out_size, void* d_ws, size_t ws_size,
                              hipStream_t stream)
{
  const float* img   = (const float*)d_in[0];
  const float* bfeat = (const float*)d_in[1];
  const float* wb    = (const float*)d_in[2];
  const float* bb    = (const float*)d_in[3];
  const float* gam   = (const float*)d_in[4];
  const float* bet   = (const float*)d_in[5];
  const float* wm    = (const float*)d_in[6];

  float* out_img = (float*)d_out;                 // [4,3,192,192]
  float* out_msp = (float*)d_out + 442368;        // [4,256,192,192]
  float* out_pal = (float*)d_out + 38191104;      // [4,3,256,1,1]

  char* w = (char*)d_ws;
  float*     ws_x       = (float*)(w);                     // 9,437,184 B (dead after k2 -> reused for k3 partials)
  double*    ws_part    = (double*)(w + 9437184);          //   147,456 B
  double*    ws_st64    = (double*)(w + 9584640);          //       256 B
  float*     ws_st32    = (float*)(w + 9584896);           //       128 B
  unsigned*  ws_flagcnt = (unsigned*)(w + 9585152);        //       256 B pad
  FlagEntry* ws_entries = (FlagEntry*)(w + 9585408);       // 2,359,296 B
  unsigned*  ws_cidx    = (unsigned*)(w + 11944704);       // 2,359,296 B
  float*     ws_cw      = (float*)(w + 14304000);          // 9,437,184 B
  float*     ws_nd      = ws_x;                            // aliases ws_x (x dead after k2)
  short*     ws_bfrag   = (short*)(w + 23741184);          //    32,768 B

  k1_conv<<<dim3(576), dim3(256), 0, stream>>>(bfeat, wb, bb, ws_x, ws_part);
  k1x_aux<<<dim3(2), dim3(256), 0, stream>>>(ws_part, gam, bet, ws_st64, ws_st32,
                                             wm, ws_bfrag, ws_flagcnt);
  k2_main<<<dim3(2304), dim3(256), 0, stream>>>(ws_x, ws_bfrag, ws_st32, out_msp,
                                                ws_cidx, ws_cw, ws_flagcnt, ws_entries);
  k2b_fix<<<dim3(4096), dim3(64), 0, stream>>>(bfeat, wb, bb, wm, ws_st64,
                                               ws_flagcnt, ws_entries, out_msp, ws_cidx, ws_cw);
  k3_accum<<<dim3(576), dim3(256), 0, stream>>>((const uint4*)ws_cidx, (const float4*)ws_cw,
                                                img, ws_nd);
  k4_pal<<<dim3(4), dim3(256), 0, stream>>>(ws_nd, out_pal);
  k5_img<<<dim3(576), dim3(256), 0, stream>>>((const uint4*)ws_cidx, (const float4*)ws_cw,
                                              out_pal, out_img);
}